// Round 1
// baseline (393.118 us; speedup 1.0000x reference)
//
#include <hip/hip_runtime.h>

#define H 16
#define S 2048
#define DM 1024
#define HD 64
#define NB 2

typedef __attribute__((ext_vector_type(8))) short short8_t;
typedef __attribute__((ext_vector_type(4))) float f32x4;

static __device__ __forceinline__ unsigned short f2bf(float f){
  union { float f; unsigned u; } x; x.f = f;
  unsigned r = x.u + 0x7fffu + ((x.u >> 16) & 1u);
  return (unsigned short)(r >> 16);
}

// ---------------- conversions ----------------
__global__ void conv_bf16(const float* __restrict__ in, unsigned short* __restrict__ out, int n){
  int i = (blockIdx.x*blockDim.x + threadIdx.x)*4;
  if (i >= n) return;
  float4 v = *(const float4*)(in + i);
  ushort4 o; o.x=f2bf(v.x); o.y=f2bf(v.y); o.z=f2bf(v.z); o.w=f2bf(v.w);
  *(ushort4*)(out + i) = o;
}

__global__ void conv_mask(const int* __restrict__ in, unsigned char* __restrict__ out, int n){
  int i = (blockIdx.x*blockDim.x + threadIdx.x)*4;
  if (i >= n) return;
  int4 v = *(const int4*)(in + i);
  unsigned p = (v.x!=0 ? 1u:0u) | (v.y!=0 ? 256u:0u) | (v.z!=0 ? 65536u:0u) | (v.w!=0 ? 16777216u:0u);
  *(unsigned*)(out + i) = p;
}

// Wt[c][r] = bf16(W[r][c]) ; W is DM x DM
__global__ void wtrans(const float* __restrict__ W, unsigned short* __restrict__ Wt){
  __shared__ float t[32][33];
  int tx = threadIdx.x & 31, ty = threadIdx.x >> 5;
  int r0 = blockIdx.y*32, c0 = blockIdx.x*32;
  #pragma unroll
  for (int i=0;i<32;i+=8) t[ty+i][tx] = W[(size_t)(r0+ty+i)*DM + c0+tx];
  __syncthreads();
  #pragma unroll
  for (int i=0;i<32;i+=8) Wt[(size_t)(c0+ty+i)*DM + r0+tx] = f2bf(t[tx][ty+i]);
}

// ---------------- GEMM: C = A[M,K] @ Bt[N,K]^T (+bias) ----------------
// MODE 0: out bf16, head-split [B,H,S,HD], val=(acc+bias)*scale
// MODE 1: operands swapped -> acc rows are N; out bf16 transposed [B,H,HD,S]
// MODE 2: out fp32 row-major [M,N] + bias
template<int MODE>
__global__ __launch_bounds__(256) void gemm_bf16(const unsigned short* __restrict__ A,
    const unsigned short* __restrict__ Bt, const float* __restrict__ bias,
    void* __restrict__ dst, float scale, int M, int N, int K){
  __shared__ __align__(16) char Alds[8192];
  __shared__ __align__(16) char Blds[8192];
  const int tid = threadIdx.x, lane = tid & 63, wv = tid >> 6;
  const int l15 = lane & 15, l4 = lane >> 4;
  const int wr = wv >> 1, wc = wv & 1;
  const int m0 = blockIdx.y*128, n0 = blockIdx.x*128;

  f32x4 acc[4][4];
  #pragma unroll
  for (int i=0;i<4;i++)
    #pragma unroll
    for (int j=0;j<4;j++) acc[i][j] = (f32x4){0.f,0.f,0.f,0.f};

  for (int k0 = 0; k0 < K; k0 += 32){
    #pragma unroll
    for (int i=0;i<2;i++){
      int u = tid + i*256;            // 16B unit index, 512 units per 8KB tile
      int row = u >> 2; int cb = (u & 3)*16;
      int d = (u*16) ^ ((row & 7) << 4);   // XOR swizzle (G4), bijective, same on read
      *(uint4*)(Alds + d) = *(const uint4*)((const char*)A  + ((size_t)(m0+row)*K + k0)*2 + cb);
      *(uint4*)(Blds + d) = *(const uint4*)((const char*)Bt + ((size_t)(n0+row)*K + k0)*2 + cb);
    }
    __syncthreads();
    short8_t av[4], bv[4];
    #pragma unroll
    for (int i=0;i<4;i++){
      int ra = wr*64 + i*16 + l15;
      av[i] = *(const short8_t*)(Alds + ((ra*64 + l4*16) ^ ((ra&7)<<4)));
      int rb = wc*64 + i*16 + l15;
      bv[i] = *(const short8_t*)(Blds + ((rb*64 + l4*16) ^ ((rb&7)<<4)));
    }
    #pragma unroll
    for (int i=0;i<4;i++)
      #pragma unroll
      for (int j=0;j<4;j++){
        if constexpr (MODE == 1)
          acc[i][j] = __builtin_amdgcn_mfma_f32_16x16x32_bf16(bv[i], av[j], acc[i][j], 0,0,0);
        else
          acc[i][j] = __builtin_amdgcn_mfma_f32_16x16x32_bf16(av[i], bv[j], acc[i][j], 0,0,0);
      }
    __syncthreads();
  }

  if constexpr (MODE == 0){
    unsigned short* out = (unsigned short*)dst;
    #pragma unroll
    for (int i=0;i<4;i++)
      #pragma unroll
      for (int j=0;j<4;j++)
        #pragma unroll
        for (int jr=0;jr<4;jr++){
          int m = m0 + wr*64 + i*16 + l4*4 + jr;
          int n = n0 + wc*64 + j*16 + l15;
          float v = (acc[i][j][jr] + bias[n]) * scale;
          int bb = m >> 11, s = m & (S-1), hh = n >> 6, d = n & 63;
          out[(((size_t)bb*H + hh)*S + s)*HD + d] = f2bf(v);
        }
  } else if constexpr (MODE == 1){
    unsigned short* out = (unsigned short*)dst;
    #pragma unroll
    for (int i=0;i<4;i++)
      #pragma unroll
      for (int j=0;j<4;j++)
        #pragma unroll
        for (int jr=0;jr<4;jr++){
          int n = n0 + wc*64 + i*16 + l4*4 + jr;   // rows = N dim
          int m = m0 + wr*64 + j*16 + l15;         // cols = M dim
          float v = acc[i][j][jr] + bias[n];
          int bb = m >> 11, s = m & (S-1), hh = n >> 6, d = n & 63;
          out[(((size_t)bb*H + hh)*HD + d)*S + s] = f2bf(v);
        }
  } else {
    float* out = (float*)dst;
    #pragma unroll
    for (int i=0;i<4;i++)
      #pragma unroll
      for (int j=0;j<4;j++)
        #pragma unroll
        for (int jr=0;jr<4;jr++){
          int m = m0 + wr*64 + i*16 + l4*4 + jr;
          int n = n0 + wc*64 + j*16 + l15;
          out[(size_t)m*N + n] = acc[i][j][jr] + bias[n];
        }
  }
}

// ---------------- flash attention ----------------
// Q [B,H,S,HD] bf16 (pre-scaled 1/8), K [B,H,S,HD] bf16, VT [B,H,HD,S] bf16,
// mask8 [B,S,S] u8, X out [B,S,DM] bf16
__global__ __launch_bounds__(256) void attn_fwd(const unsigned short* __restrict__ Q,
    const unsigned short* __restrict__ Kp, const unsigned short* __restrict__ VT,
    const unsigned char* __restrict__ m8, unsigned short* __restrict__ X){
  __shared__ __align__(16) char Klds[8192];
  __shared__ __align__(16) char Vlds[8192];
  __shared__ __align__(16) char Plds[4][2048];
  const int tid = threadIdx.x, lane = tid & 63, wv = tid >> 6;
  const int l15 = lane & 15, l4 = lane >> 4;
  const int bh = blockIdx.y, b = bh >> 4, hh = bh & 15;
  const int q0 = blockIdx.x * 64;

  const unsigned short* Qb = Q + ((size_t)bh*S + q0 + wv*16)*HD;
  short8_t qf[2];
  #pragma unroll
  for (int ks=0;ks<2;ks++)
    qf[ks] = *(const short8_t*)(Qb + (size_t)l15*HD + ks*32 + l4*8);

  f32x4 o[4];
  float mrun[4], lrun[4];
  #pragma unroll
  for (int j=0;j<4;j++){ o[j] = (f32x4){0.f,0.f,0.f,0.f}; mrun[j] = -1e30f; lrun[j] = 0.f; }

  const char* Ksrc = (const char*)(Kp + (size_t)bh*S*HD);
  const char* Vsrc = (const char*)(VT + (size_t)bh*HD*S);
  const unsigned char* mb = m8 + ((size_t)b << 22);
  const int qbase = q0 + wv*16 + l4*4;
  char* Pw = Plds[wv];

  for (int kv0 = 0; kv0 < S; kv0 += 64){
    #pragma unroll
    for (int i=0;i<2;i++){
      int u = tid + i*256;
      int row = u >> 3, c16 = u & 7;
      int d = (u*16) ^ ((row & 7) << 4);
      *(uint4*)(Klds + d) = *(const uint4*)(Ksrc + ((size_t)(kv0+row)*HD + c16*8)*2);
      *(uint4*)(Vlds + d) = *(const uint4*)(Vsrc + ((size_t)row*S + kv0 + c16*8)*2);
    }
    __syncthreads();

    f32x4 sc[4];
    #pragma unroll
    for (int nt=0;nt<4;nt++){
      f32x4 c = (f32x4){0.f,0.f,0.f,0.f};
      #pragma unroll
      for (int ks=0;ks<2;ks++){
        int rk = nt*16 + l15;
        short8_t kf = *(const short8_t*)(Klds + ((rk*128 + ks*64 + l4*16) ^ ((rk&7)<<4)));
        c = __builtin_amdgcn_mfma_f32_16x16x32_bf16(qf[ks], kf, c, 0,0,0);
      }
      sc[nt] = c;
    }

    #pragma unroll
    for (int nt=0;nt<4;nt++)
      #pragma unroll
      for (int jr=0;jr<4;jr++){
        unsigned char mm = mb[(size_t)(qbase+jr)*S + kv0 + nt*16 + l15];
        if (!mm) sc[nt][jr] = -1e9f;
      }

    float mnew[4], rscale[4];
    #pragma unroll
    for (int jr=0;jr<4;jr++){
      float r = fmaxf(fmaxf(sc[0][jr], sc[1][jr]), fmaxf(sc[2][jr], sc[3][jr]));
      r = fmaxf(r, __shfl_xor(r, 1));
      r = fmaxf(r, __shfl_xor(r, 2));
      r = fmaxf(r, __shfl_xor(r, 4));
      r = fmaxf(r, __shfl_xor(r, 8));
      mnew[jr] = fmaxf(mrun[jr], r);
      rscale[jr] = __expf(mrun[jr] - mnew[jr]);
    }

    #pragma unroll
    for (int jr=0;jr<4;jr++){
      float ssum = 0.f;
      #pragma unroll
      for (int nt=0;nt<4;nt++){
        float p = __expf(sc[nt][jr] - mnew[jr]);
        sc[nt][jr] = p;
        ssum += p;
      }
      ssum += __shfl_xor(ssum, 1);
      ssum += __shfl_xor(ssum, 2);
      ssum += __shfl_xor(ssum, 4);
      ssum += __shfl_xor(ssum, 8);
      lrun[jr] = lrun[jr]*rscale[jr] + ssum;
      mrun[jr] = mnew[jr];
    }

    #pragma unroll
    for (int nt2=0;nt2<4;nt2++)
      #pragma unroll
      for (int jr=0;jr<4;jr++) o[nt2][jr] *= rscale[jr];

    #pragma unroll
    for (int nt=0;nt<4;nt++)
      #pragma unroll
      for (int jr=0;jr<4;jr++){
        int row = l4*4 + jr;
        int byte = (row*128 + (nt*16 + l15)*2) ^ ((row & 7) << 4);
        *(unsigned short*)(Pw + byte) = f2bf(sc[nt][jr]);
      }

    #pragma unroll
    for (int ks2=0;ks2<2;ks2++){
      short8_t pf = *(const short8_t*)(Pw + ((l15*128 + ks2*64 + l4*16) ^ ((l15&7)<<4)));
      #pragma unroll
      for (int nt2=0;nt2<4;nt2++){
        int rv = nt2*16 + l15;
        short8_t vf = *(const short8_t*)(Vlds + ((rv*128 + ks2*64 + l4*16) ^ ((rv&7)<<4)));
        o[nt2] = __builtin_amdgcn_mfma_f32_16x16x32_bf16(pf, vf, o[nt2], 0,0,0);
      }
    }
    __syncthreads();
  }

  #pragma unroll
  for (int nt2=0;nt2<4;nt2++)
    #pragma unroll
    for (int jr=0;jr<4;jr++){
      float v = o[nt2][jr] / lrun[jr];
      int qrow = qbase + jr;
      X[((size_t)b*S + qrow)*DM + hh*HD + nt2*16 + l15] = f2bf(v);
    }
}

// ---------------- launch ----------------
extern "C" void kernel_launch(void* const* d_in, const int* in_sizes, int n_in,
                              void* d_out, int out_size, void* d_ws, size_t ws_size,
                              hipStream_t stream){
  const float* query = (const float*)d_in[0];
  const float* key   = (const float*)d_in[1];
  const float* value = (const float*)d_in[2];
  const int*   mask  = (const int*)d_in[3];
  const float* Wq = (const float*)d_in[4];
  const float* bq = (const float*)d_in[5];
  const float* Wk = (const float*)d_in[6];
  const float* bk = (const float*)d_in[7];
  const float* Wv = (const float*)d_in[8];
  const float* bvp= (const float*)d_in[9];
  const float* Wo = (const float*)d_in[10];
  const float* bo = (const float*)d_in[11];

  const size_t NE = (size_t)NB*S*DM;       // 4194304 activation elems
  const size_t WE = (size_t)DM*DM;         // 1048576 weight elems
  const size_t ME = (size_t)NB*S*S;        // 8388608 mask elems

  char* w = (char*)d_ws;
  unsigned short* qb  = (unsigned short*)w; w += NE*2;
  unsigned short* kb  = (unsigned short*)w; w += NE*2;
  unsigned short* vb  = (unsigned short*)w; w += NE*2;
  unsigned short* WqT = (unsigned short*)w; w += WE*2;
  unsigned short* WkT = (unsigned short*)w; w += WE*2;
  unsigned short* WvT = (unsigned short*)w; w += WE*2;
  unsigned short* WoT = (unsigned short*)w; w += WE*2;
  unsigned char*  m8  = (unsigned char*)w;  w += ME;
  unsigned short* Qp  = (unsigned short*)w; w += NE*2;
  unsigned short* Kp  = (unsigned short*)w; w += NE*2;
  unsigned short* VTp = (unsigned short*)w; w += NE*2;
  unsigned short* xb  = (unsigned short*)w; w += NE*2;

  conv_bf16<<<NE/1024, 256, 0, stream>>>(query, qb, (int)NE);
  conv_bf16<<<NE/1024, 256, 0, stream>>>(key,   kb, (int)NE);
  conv_bf16<<<NE/1024, 256, 0, stream>>>(value, vb, (int)NE);
  dim3 tg(DM/32, DM/32);
  wtrans<<<tg, 256, 0, stream>>>(Wq, WqT);
  wtrans<<<tg, 256, 0, stream>>>(Wk, WkT);
  wtrans<<<tg, 256, 0, stream>>>(Wv, WvT);
  wtrans<<<tg, 256, 0, stream>>>(Wo, WoT);
  conv_mask<<<ME/1024, 256, 0, stream>>>(mask, m8, (int)ME);

  dim3 gg(DM/128, (NB*S)/128);   // (8, 32)
  gemm_bf16<0><<<gg, 256, 0, stream>>>(qb, WqT, bq,  Qp,  0.125f, NB*S, DM, DM);
  gemm_bf16<0><<<gg, 256, 0, stream>>>(kb, WkT, bk,  Kp,  1.0f,   NB*S, DM, DM);
  gemm_bf16<1><<<gg, 256, 0, stream>>>(vb, WvT, bvp, VTp, 1.0f,   NB*S, DM, DM);

  attn_fwd<<<dim3(S/64, NB*H), 256, 0, stream>>>(Qp, Kp, VTp, m8, xb);

  gemm_bf16<2><<<gg, 256, 0, stream>>>(xb, WoT, bo, d_out, 1.0f, NB*S, DM, DM);
}

// Round 2
// 310.600 us; speedup vs baseline: 1.2657x; 1.2657x over previous
//
#include <hip/hip_runtime.h>
#include <hip/hip_bf16.h>

#define H 16
#define S 2048
#define DM 1024
#define HD 64
#define NB 2

typedef __attribute__((ext_vector_type(8))) short short8_t;
typedef __attribute__((ext_vector_type(4))) float f32x4;

static __device__ __forceinline__ unsigned short f2bf(float f){
  union { float f; unsigned u; } x; x.f = f;
  unsigned r = x.u + 0x7fffu + ((x.u >> 16) & 1u);
  return (unsigned short)(r >> 16);
}

static __device__ __forceinline__ unsigned pk2(float a, float b){
  union { __hip_bfloat16 h; unsigned short u; } x, y;
  x.h = __hip_bfloat16(a); y.h = __hip_bfloat16(b);
  return (unsigned)x.u | ((unsigned)y.u << 16);
}

// ---------------- conversions ----------------
__global__ void conv_bf16(const float* __restrict__ in, unsigned short* __restrict__ out, int n){
  int i = (blockIdx.x*blockDim.x + threadIdx.x)*4;
  if (i >= n) return;
  float4 v = *(const float4*)(in + i);
  ushort4 o; o.x=f2bf(v.x); o.y=f2bf(v.y); o.z=f2bf(v.z); o.w=f2bf(v.w);
  *(ushort4*)(out + i) = o;
}

// pack mask ints into bit-mask u64 (bit j of word w = mask[w*64+j] != 0)
__global__ void conv_mask_bits(const int* __restrict__ in, unsigned long long* __restrict__ out){
  size_t i = (size_t)blockIdx.x*256 + threadIdx.x;
  int v = in[i];
  unsigned long long bm = __ballot(v != 0);
  if ((threadIdx.x & 63) == 0) out[i >> 6] = bm;
}

// Wt[c][r] = bf16(W[r][c]) ; W is DM x DM
__global__ void wtrans(const float* __restrict__ W, unsigned short* __restrict__ Wt){
  __shared__ float t[32][33];
  int tx = threadIdx.x & 31, ty = threadIdx.x >> 5;
  int r0 = blockIdx.y*32, c0 = blockIdx.x*32;
  #pragma unroll
  for (int i=0;i<32;i+=8) t[ty+i][tx] = W[(size_t)(r0+ty+i)*DM + c0+tx];
  __syncthreads();
  #pragma unroll
  for (int i=0;i<32;i+=8) Wt[(size_t)(c0+ty+i)*DM + r0+tx] = f2bf(t[tx][ty+i]);
}

// ---------------- GEMM: C = A[M,K] @ Bt[N,K]^T (+bias) ----------------
// 128x128 tile, BK=64, 8 waves (2x4), double-buffered single-barrier pipeline.
// MODE 0: out bf16 head-split [B,H,S,HD], val=(acc+bias)*scale
// MODE 1: swapped operands -> out bf16 transposed [B,H,HD,S]
// MODE 2: out fp32 row-major [M,N] + bias
template<int MODE>
__global__ __launch_bounds__(512) void gemm_bf16(const unsigned short* __restrict__ A,
    const unsigned short* __restrict__ Bt, const float* __restrict__ bias,
    void* __restrict__ dst, float scale, int M, int N, int K){
  __shared__ __align__(16) char Alds[2][16384];
  __shared__ __align__(16) char Blds[2][16384];
  const int tid = threadIdx.x, lane = tid & 63, wv = tid >> 6;
  const int l15 = lane & 15, l4 = lane >> 4;
  const int wr = wv >> 2, wc = wv & 3;       // 2x4 wave grid; wave owns 64 rows x 32 cols
  const int m0 = blockIdx.y*128, n0 = blockIdx.x*128;

  f32x4 acc[4][2];
  #pragma unroll
  for (int i=0;i<4;i++)
    #pragma unroll
    for (int j=0;j<2;j++) acc[i][j] = (f32x4){0.f,0.f,0.f,0.f};

  // staging: 1024 units of 16B per matrix; thread owns units tid and tid+512
  const int r0 = tid >> 3, c0 = (tid & 7) * 16;   // unit tid: row r0, bytes c0
  const char* Ap  = (const char*)A  + (size_t)(m0 + r0)*K*2 + c0;
  const char* Ap2 = (const char*)A  + (size_t)(m0 + r0 + 64)*K*2 + c0;
  const char* Bp  = (const char*)Bt + (size_t)(n0 + r0)*K*2 + c0;
  const char* Bp2 = (const char*)Bt + (size_t)(n0 + r0 + 64)*K*2 + c0;
  const int d0 = (tid*16) ^ ((r0 & 7) << 4);      // (r0+64)&7 == r0&7 -> second unit at d0+8192

  uint4 a0 = *(const uint4*)Ap, a1 = *(const uint4*)Ap2;
  uint4 b0 = *(const uint4*)Bp, b1 = *(const uint4*)Bp2;
  *(uint4*)(Alds[0]+d0) = a0; *(uint4*)(Alds[0]+d0+8192) = a1;
  *(uint4*)(Blds[0]+d0) = b0; *(uint4*)(Blds[0]+d0+8192) = b1;
  __syncthreads();

  const int NT = K/64;
  int p = 0;
  for (int t = 0; t < NT; ++t){
    if (t+1 < NT){
      a0 = *(const uint4*)(Ap  + (size_t)(t+1)*128);
      a1 = *(const uint4*)(Ap2 + (size_t)(t+1)*128);
      b0 = *(const uint4*)(Bp  + (size_t)(t+1)*128);
      b1 = *(const uint4*)(Bp2 + (size_t)(t+1)*128);
    }
    #pragma unroll
    for (int ks=0; ks<2; ks++){
      short8_t av[4], bv[2];
      #pragma unroll
      for (int i=0;i<4;i++){
        int ra = wr*64 + i*16 + l15;
        av[i] = *(const short8_t*)(Alds[p] + ((ra*128 + ks*64 + l4*16) ^ ((ra&7)<<4)));
      }
      #pragma unroll
      for (int j=0;j<2;j++){
        int rb = wc*32 + j*16 + l15;
        bv[j] = *(const short8_t*)(Blds[p] + ((rb*128 + ks*64 + l4*16) ^ ((rb&7)<<4)));
      }
      #pragma unroll
      for (int i=0;i<4;i++)
        #pragma unroll
        for (int j=0;j<2;j++){
          if constexpr (MODE == 1)
            acc[i][j] = __builtin_amdgcn_mfma_f32_16x16x32_bf16(bv[j], av[i], acc[i][j], 0,0,0);
          else
            acc[i][j] = __builtin_amdgcn_mfma_f32_16x16x32_bf16(av[i], bv[j], acc[i][j], 0,0,0);
        }
    }
    if (t+1 < NT){
      *(uint4*)(Alds[p^1]+d0) = a0; *(uint4*)(Alds[p^1]+d0+8192) = a1;
      *(uint4*)(Blds[p^1]+d0) = b0; *(uint4*)(Blds[p^1]+d0+8192) = b1;
    }
    __syncthreads();
    p ^= 1;
  }

  if constexpr (MODE == 0){
    unsigned short* out = (unsigned short*)dst;
    #pragma unroll
    for (int i=0;i<4;i++)
      #pragma unroll
      for (int j=0;j<2;j++)
        #pragma unroll
        for (int jr=0;jr<4;jr++){
          int m = m0 + wr*64 + i*16 + l4*4 + jr;
          int n = n0 + wc*32 + j*16 + l15;
          float v = (acc[i][j][jr] + bias[n]) * scale;
          int bb = m >> 11, s = m & (S-1), hh = n >> 6, d = n & 63;
          out[(((size_t)bb*H + hh)*S + s)*HD + d] = f2bf(v);
        }
  } else if constexpr (MODE == 1){
    unsigned short* out = (unsigned short*)dst;
    #pragma unroll
    for (int i=0;i<4;i++)
      #pragma unroll
      for (int j=0;j<2;j++)
        #pragma unroll
        for (int jr=0;jr<4;jr++){
          int n = n0 + wc*32 + j*16 + l4*4 + jr;
          int m = m0 + wr*64 + i*16 + l15;
          float v = acc[i][j][jr] + bias[n];
          int bb = m >> 11, s = m & (S-1), hh = n >> 6, d = n & 63;
          out[(((size_t)bb*H + hh)*HD + d)*S + s] = f2bf(v);
        }
  } else {
    float* out = (float*)dst;
    #pragma unroll
    for (int i=0;i<4;i++)
      #pragma unroll
      for (int j=0;j<2;j++)
        #pragma unroll
        for (int jr=0;jr<4;jr++){
          int m = m0 + wr*64 + i*16 + l4*4 + jr;
          int n = n0 + wc*32 + j*16 + l15;
          out[(size_t)m*N + n] = acc[i][j][jr] + bias[n];
        }
  }
}

// ---------------- flash attention ----------------
// Swapped-operand scheme: scores = mfma(K,Q) -> lane holds q = lane&15 (stats lane-local),
// O = mfma(VT,P) -> same q column. 128 q-rows/block, 8 waves x 16 rows, KV tiles of 64,
// double-buffered LDS, one barrier per tile.
// Q [B,H,S,HD] bf16 (pre-scaled 1/8), K [B,H,S,HD], VT [B,H,HD,S], Mb [B,S,S/64] u64,
// X out [B,S,DM] bf16
__global__ __launch_bounds__(512, 4) void attn_fwd(const unsigned short* __restrict__ Q,
    const unsigned short* __restrict__ Kp, const unsigned short* __restrict__ VT,
    const unsigned long long* __restrict__ Mb, unsigned short* __restrict__ X){
  __shared__ __align__(16) char Klds[2][8192];
  __shared__ __align__(16) char Vlds[2][8192];
  const int tid = threadIdx.x, lane = tid & 63, wv = tid >> 6;
  const int l15 = lane & 15, l4 = lane >> 4;
  const int hi = l4 >> 1, lo = l4 & 1;
  const int bh = blockIdx.y, b = bh >> 4, hh = bh & 15;
  const int q0 = blockIdx.x * 128;
  const int qrow = q0 + wv*16 + l15;

  // Q fragment (B-operand): lane holds Q[qrow][d = ks*32 + l4*8 + j]
  const unsigned short* Qb = Q + ((size_t)bh*S + qrow)*HD;
  short8_t qf0 = *(const short8_t*)(Qb + l4*8);
  short8_t qf1 = *(const short8_t*)(Qb + 32 + l4*8);

  f32x4 o[4];
  #pragma unroll
  for (int j=0;j<4;j++) o[j] = (f32x4){0.f,0.f,0.f,0.f};
  float mrun = -3.0e38f, lrun = 0.f;

  const char* Ksrc = (const char*)(Kp + (size_t)bh*S*HD);
  const char* Vsrc = (const char*)(VT + (size_t)bh*HD*S);
  const unsigned long long* mrow = Mb + ((size_t)b*S + qrow)*(S/64);

  // staging: 512 threads, one 16B K-unit + one 16B V-unit each per tile
  const int srow = tid >> 3, sc16 = tid & 7;
  const int sdst = (tid*16) ^ ((srow & 7) << 4);
  const char* kptr = Ksrc + (size_t)srow*HD*2 + sc16*16;   // += 8192/tile
  const char* vptr = Vsrc + (size_t)srow*S*2 + sc16*16;    // += 128/tile

  uint4 kr = *(const uint4*)kptr;
  uint4 vr = *(const uint4*)vptr;
  unsigned long long w64 = mrow[0];
  *(uint4*)(Klds[0] + sdst) = kr;
  *(uint4*)(Vlds[0] + sdst) = vr;
  __syncthreads();
  kptr += 8192; vptr += 128;

  const int NT = S/64;
  int p = 0;
  for (int t = 0; t < NT; ++t){
    unsigned long long wcur = w64;
    if (t+1 < NT){
      kr = *(const uint4*)kptr;  kptr += 8192;
      vr = *(const uint4*)vptr;  vptr += 128;
      w64 = mrow[t+1];
    }

    // ---- QK^T: sc[nt] rows kv = nt*16 + l4*4 + jr, col q = l15 ----
    f32x4 sct[4];
    #pragma unroll
    for (int nt=0;nt<4;nt++){
      int rk = nt*16 + l15;
      const char* kb = Klds[p];
      short8_t kf0 = *(const short8_t*)(kb + ((rk*128 +      l4*16) ^ ((rk&7)<<4)));
      short8_t kf1 = *(const short8_t*)(kb + ((rk*128 + 64 + l4*16) ^ ((rk&7)<<4)));
      f32x4 c = (f32x4){0.f,0.f,0.f,0.f};
      c = __builtin_amdgcn_mfma_f32_16x16x32_bf16(kf0, qf0, c, 0,0,0);
      c = __builtin_amdgcn_mfma_f32_16x16x32_bf16(kf1, qf1, c, 0,0,0);
      sct[nt] = c;
    }

    // ---- online softmax (stats lane-local for q = l15) ----
    float tmax = -3.0e38f;
    #pragma unroll
    for (int nt=0;nt<4;nt++)
      #pragma unroll
      for (int jr=0;jr<4;jr++) tmax = fmaxf(tmax, sct[nt][jr]);
    tmax = fmaxf(tmax, __shfl_xor(tmax, 16));
    tmax = fmaxf(tmax, __shfl_xor(tmax, 32));
    float mnew = fmaxf(mrun, tmax);
    float rs = __expf(mrun - mnew);

    unsigned long long wsh = wcur >> (l4*4);
    float ssum = 0.f;
    #pragma unroll
    for (int nt=0;nt<4;nt++)
      #pragma unroll
      for (int jr=0;jr<4;jr++){
        float e = __expf(sct[nt][jr] - mnew);
        e = ((wsh >> (nt*16 + jr)) & 1ull) ? e : 0.f;
        sct[nt][jr] = e;
        ssum += e;
      }
    ssum += __shfl_xor(ssum, 16);
    ssum += __shfl_xor(ssum, 32);
    lrun = lrun*rs + ssum;
    mrun = mnew;

    #pragma unroll
    for (int nt2=0;nt2<4;nt2++)
      #pragma unroll
      for (int jr=0;jr<4;jr++) o[nt2][jr] *= rs;

    // ---- P -> bf16 PV fragments via pack + shfl (lane holds kv = nt*16+l4*4+jr) ----
    unsigned w[4][2];
    #pragma unroll
    for (int nt=0;nt<4;nt++){
      w[nt][0] = pk2(sct[nt][0], sct[nt][1]);
      w[nt][1] = pk2(sct[nt][2], sct[nt][3]);
    }
    int sA = l15 + lo*32;   // source lane, s=0
    int sB = sA + 16;       // s=1
    unsigned r[4][2][2];
    #pragma unroll
    for (int a=0;a<4;a++)
      #pragma unroll
      for (int bb2=0;bb2<2;bb2++){
        r[a][bb2][0] = (unsigned)__shfl((int)w[a][bb2], sA);
        r[a][bb2][1] = (unsigned)__shfl((int)w[a][bb2], sB);
      }

    // ---- PV: o = mfma(VT, P) ----
    #pragma unroll
    for (int ks2=0; ks2<2; ks2++){
      union { short8_t s; unsigned w[4]; } pf;
      #pragma unroll
      for (int u=0;u<4;u++){
        unsigned va = r[ks2*2    ][u&1][u>>1];
        unsigned vb = r[ks2*2 + 1][u&1][u>>1];
        pf.w[u] = hi ? vb : va;
      }
      #pragma unroll
      for (int nt2=0;nt2<4;nt2++){
        int rv = nt2*16 + l15;
        short8_t vf = *(const short8_t*)(Vlds[p] + ((rv*128 + ks2*64 + l4*16) ^ ((rv&7)<<4)));
        o[nt2] = __builtin_amdgcn_mfma_f32_16x16x32_bf16(vf, pf.s, o[nt2], 0,0,0);
      }
    }

    if (t+1 < NT){
      *(uint4*)(Klds[p^1] + sdst) = kr;
      *(uint4*)(Vlds[p^1] + sdst) = vr;
    }
    __syncthreads();
    p ^= 1;
  }

  // ---- epilogue: stage O through LDS for coalesced global writes ----
  float inv = 1.0f / lrun;
  char* ows = ((char*)Klds) + wv*2048;   // 8 waves x 2KB inside Klds[2]
  #pragma unroll
  for (int nt2=0;nt2<4;nt2++){
    unsigned wA = pk2(o[nt2][0]*inv, o[nt2][1]*inv);
    unsigned wB = pk2(o[nt2][2]*inv, o[nt2][3]*inv);
    int base = (l15*128 + nt2*32 + l4*8) ^ ((l15&7)<<4);
    *(unsigned*)(ows + base)     = wA;
    *(unsigned*)(ows + base + 4) = wB;
  }
  __syncthreads();
  #pragma unroll
  for (int i=0;i<2;i++){
    int unit = lane + 64*i;
    int rr = unit >> 3, cc = unit & 7;
    uint4 vv = *(const uint4*)(ows + ((rr*128 + cc*16) ^ ((rr&7)<<4)));
    *(uint4*)(X + ((size_t)b*S + q0 + wv*16 + rr)*DM + hh*HD + cc*8) = vv;
  }
}

// ---------------- launch ----------------
extern "C" void kernel_launch(void* const* d_in, const int* in_sizes, int n_in,
                              void* d_out, int out_size, void* d_ws, size_t ws_size,
                              hipStream_t stream){
  const float* query = (const float*)d_in[0];
  const float* key   = (const float*)d_in[1];
  const float* value = (const float*)d_in[2];
  const int*   mask  = (const int*)d_in[3];
  const float* Wq = (const float*)d_in[4];
  const float* bq = (const float*)d_in[5];
  const float* Wk = (const float*)d_in[6];
  const float* bk = (const float*)d_in[7];
  const float* Wv = (const float*)d_in[8];
  const float* bvp= (const float*)d_in[9];
  const float* Wo = (const float*)d_in[10];
  const float* bo = (const float*)d_in[11];

  const size_t NE = (size_t)NB*S*DM;
  const size_t WE = (size_t)DM*DM;
  const size_t ME = (size_t)NB*S*S;

  char* w = (char*)d_ws;
  unsigned short* qb  = (unsigned short*)w; w += NE*2;
  unsigned short* kb  = (unsigned short*)w; w += NE*2;
  unsigned short* vb  = (unsigned short*)w; w += NE*2;
  unsigned short* WqT = (unsigned short*)w; w += WE*2;
  unsigned short* WkT = (unsigned short*)w; w += WE*2;
  unsigned short* WvT = (unsigned short*)w; w += WE*2;
  unsigned short* WoT = (unsigned short*)w; w += WE*2;
  unsigned long long* mbits = (unsigned long long*)w; w += (ME/64)*8;
  unsigned short* Qp  = (unsigned short*)w; w += NE*2;
  unsigned short* Kp  = (unsigned short*)w; w += NE*2;
  unsigned short* VTp = (unsigned short*)w; w += NE*2;
  unsigned short* xb  = (unsigned short*)w; w += NE*2;

  conv_bf16<<<NE/1024, 256, 0, stream>>>(query, qb, (int)NE);
  conv_bf16<<<NE/1024, 256, 0, stream>>>(key,   kb, (int)NE);
  conv_bf16<<<NE/1024, 256, 0, stream>>>(value, vb, (int)NE);
  dim3 tg(DM/32, DM/32);
  wtrans<<<tg, 256, 0, stream>>>(Wq, WqT);
  wtrans<<<tg, 256, 0, stream>>>(Wk, WkT);
  wtrans<<<tg, 256, 0, stream>>>(Wv, WvT);
  wtrans<<<tg, 256, 0, stream>>>(Wo, WoT);
  conv_mask_bits<<<ME/256, 256, 0, stream>>>(mask, mbits);

  dim3 gg(DM/128, (NB*S)/128);   // (8, 32)
  gemm_bf16<0><<<gg, 512, 0, stream>>>(qb, WqT, bq,  Qp,  0.125f, NB*S, DM, DM);
  gemm_bf16<0><<<gg, 512, 0, stream>>>(kb, WkT, bk,  Kp,  1.0f,   NB*S, DM, DM);
  gemm_bf16<1><<<gg, 512, 0, stream>>>(vb, WvT, bvp, VTp, 1.0f,   NB*S, DM, DM);

  attn_fwd<<<dim3(S/128, NB*H), 512, 0, stream>>>(Qp, Kp, VTp, mbits, xb);

  gemm_bf16<2><<<gg, 512, 0, stream>>>(xb, WoT, bo, d_out, 1.0f, NB*S, DM, DM);
}

// Round 4
// 300.688 us; speedup vs baseline: 1.3074x; 1.0330x over previous
//
#include <hip/hip_runtime.h>
#include <hip/hip_bf16.h>

#define H 16
#define S 2048
#define DM 1024
#define HD 64
#define NB 2
#define LOG2E 1.4426950408889634f

typedef __attribute__((ext_vector_type(8))) short short8_t;
typedef __attribute__((ext_vector_type(4))) float f32x4;
typedef __attribute__((ext_vector_type(16))) float f32x16;

static __device__ __forceinline__ unsigned short f2bf(float f){
  union { float f; unsigned u; } x; x.f = f;
  unsigned r = x.u + 0x7fffu + ((x.u >> 16) & 1u);
  return (unsigned short)(r >> 16);
}

static __device__ __forceinline__ unsigned pk2(float a, float b){
  union { __hip_bfloat16 h; unsigned short u; } x, y;
  x.h = __hip_bfloat16(a); y.h = __hip_bfloat16(b);
  return (unsigned)x.u | ((unsigned)y.u << 16);
}

static __device__ __forceinline__ float ex2(float x){
#if __has_builtin(__builtin_amdgcn_exp2f)
  return __builtin_amdgcn_exp2f(x);
#else
  return exp2f(x);
#endif
}

// swap upper 32 lanes of x with lower 32 lanes of y (CDNA4 v_permlane32_swap_b32)
static __device__ __forceinline__ void pswap(unsigned &x, unsigned &y){
#if defined(__gfx950__) || defined(__AMDGCN__)
  asm("v_permlane32_swap_b32 %0, %1" : "+v"(x), "+v"(y));
#else
  unsigned sx = (unsigned)__shfl_xor((int)x, 32);
  unsigned sy = (unsigned)__shfl_xor((int)y, 32);
  bool hi = (threadIdx.x & 63) >= 32;
  unsigned nx = hi ? sy : x;
  unsigned ny = hi ? y : sx;
  x = nx; y = ny;
#endif
}

// ---------------- prep: all conversions in one launch ----------------
// blocks [0,6144): q/k/v fp32->bf16 (8 elems/thread)
// blocks [6144,8192): mask -> bitmask u16 (16 ints/thread)
// blocks [8192,12288): 4x weight transpose+convert (32x32 tiles)
__global__ __launch_bounds__(256) void prep(const float* __restrict__ q, const float* __restrict__ k,
    const float* __restrict__ v, const int* __restrict__ mask,
    const float* __restrict__ Wq, const float* __restrict__ Wk, const float* __restrict__ Wv,
    const float* __restrict__ Wo,
    unsigned short* __restrict__ qb, unsigned short* __restrict__ kb, unsigned short* __restrict__ vb,
    unsigned short* __restrict__ WT, unsigned short* __restrict__ WoT,
    unsigned short* __restrict__ m16){
  __shared__ float tt[32][33];
  const int bid = blockIdx.x, tid = threadIdx.x;
  if (bid < 6144){
    const int w = bid >> 11;
    const int blk = bid & 2047;
    const float* src = (w==0)? q : (w==1)? k : v;
    unsigned short* dst = (w==0)? qb : (w==1)? kb : vb;
    size_t i = ((size_t)blk*256 + tid)*8;
    float4 x = *(const float4*)(src + i);
    float4 y = *(const float4*)(src + i + 4);
    ushort4 o1{f2bf(x.x),f2bf(x.y),f2bf(x.z),f2bf(x.w)};
    ushort4 o2{f2bf(y.x),f2bf(y.y),f2bf(y.z),f2bf(y.w)};
    *(ushort4*)(dst+i) = o1; *(ushort4*)(dst+i+4) = o2;
  } else if (bid < 8192){
    size_t base = ((size_t)(bid-6144)*256 + tid)*16;
    unsigned u = 0;
    #pragma unroll
    for (int j2=0;j2<4;j2++){
      int4 mm = *(const int4*)(mask + base + j2*4);
      u |= (mm.x!=0 ? 1u:0u) << (j2*4);
      u |= (mm.y!=0 ? 1u:0u) << (j2*4+1);
      u |= (mm.z!=0 ? 1u:0u) << (j2*4+2);
      u |= (mm.w!=0 ? 1u:0u) << (j2*4+3);
    }
    m16[base>>4] = (unsigned short)u;
  } else {
    const int wb = bid - 8192;
    const int widx = wb >> 10, t = wb & 1023;
    const float* W = (widx==0)? Wq : (widx==1)? Wk : (widx==2)? Wv : Wo;
    unsigned short* dst = (widx<3)? (WT + (size_t)widx*DM*DM) : WoT;
    const int tx = tid & 31, ty = tid >> 5;
    const int r0 = (t >> 5) * 32, c0 = (t & 31) * 32;
    #pragma unroll
    for (int i2=0;i2<32;i2+=8) tt[ty+i2][tx] = W[(size_t)(r0+ty+i2)*DM + c0+tx];
    __syncthreads();
    #pragma unroll
    for (int i2=0;i2<32;i2+=8) dst[(size_t)(c0+ty+i2)*DM + r0+tx] = f2bf(tt[tx][ty+i2]);
  }
}

// ---------------- fused QKV GEMM ----------------
// 128x128 tile, BK=32, 4 waves (2x2, wave tile 64x64), dbuf, fragment-linear LDS.
// grid (24, 32): p = blockIdx.x>>3 selects {Q,K,V}; p==2 uses swapped operands -> VT output.
__global__ __launch_bounds__(256, 2) void qkv_gemm(
    const unsigned short* __restrict__ qb, const unsigned short* __restrict__ kb,
    const unsigned short* __restrict__ vb2, const unsigned short* __restrict__ WT,
    const float* __restrict__ bq, const float* __restrict__ bk, const float* __restrict__ bv,
    unsigned short* __restrict__ Qp, unsigned short* __restrict__ Kp, unsigned short* __restrict__ VTp){
  __shared__ __align__(16) char Al[2][8192];
  __shared__ __align__(16) char Bl[2][8192];
  const int tid = threadIdx.x, lane = tid & 63, wv = tid >> 6;
  const int l15 = lane & 15, l4 = lane >> 4;
  const int wr = wv >> 1, wc = wv & 1;
  const int p = blockIdx.x >> 3;
  const int n0 = (blockIdx.x & 7) * 128;
  const int m0 = blockIdx.y * 128;
  const unsigned short* A = (p==0)? qb : (p==1)? kb : vb2;
  const unsigned short* Bt = WT + (size_t)blockIdx.x * 128 * DM;
  const float* bias = (p==0)? bq : (p==1)? bk : bv;

  f32x4 acc[4][4];
  #pragma unroll
  for (int i=0;i<4;i++)
    #pragma unroll
    for (int j=0;j<4;j++) acc[i][j] = (f32x4){0.f,0.f,0.f,0.f};

  // staging: unit u (c=u>>6, l=u&63): row = c*16 + (l&15), k8 = l>>4; LDS = u*16 (linear)
  const char* ga[2]; const char* gb[2];
  #pragma unroll
  for (int i=0;i<2;i++){
    int u = tid + i*256, c = u>>6, l = u&63;
    ga[i] = (const char*)A  + ((size_t)(m0 + c*16 + (l&15))*DM + (l>>4)*8)*2;
    gb[i] = (const char*)Bt + ((size_t)(c*16 + (l&15))*DM + (l>>4)*8)*2;
  }
  const int lo0 = tid*16, lo1 = tid*16 + 4096;

  uint4 ra0 = *(const uint4*)ga[0], ra1 = *(const uint4*)ga[1];
  uint4 rb0 = *(const uint4*)gb[0], rb1 = *(const uint4*)gb[1];
  *(uint4*)(Al[0]+lo0)=ra0; *(uint4*)(Al[0]+lo1)=ra1;
  *(uint4*)(Bl[0]+lo0)=rb0; *(uint4*)(Bl[0]+lo1)=rb1;
  __syncthreads();

  const bool sw = (p==2);
  const int NT = DM/32;
  int pb = 0;
  for (int t=0;t<NT;t++){
    if (t+1 < NT){
      ra0 = *(const uint4*)(ga[0] + (size_t)(t+1)*64);
      ra1 = *(const uint4*)(ga[1] + (size_t)(t+1)*64);
      rb0 = *(const uint4*)(gb[0] + (size_t)(t+1)*64);
      rb1 = *(const uint4*)(gb[1] + (size_t)(t+1)*64);
    }
    short8_t av[4], bvv[4];
    #pragma unroll
    for (int i=0;i<4;i++) av[i]  = *(const short8_t*)(Al[pb] + (wr*4+i)*1024 + lane*16);
    #pragma unroll
    for (int j=0;j<4;j++) bvv[j] = *(const short8_t*)(Bl[pb] + (wc*4+j)*1024 + lane*16);
    __builtin_amdgcn_s_setprio(1);
    if (sw){
      #pragma unroll
      for (int i=0;i<4;i++)
        #pragma unroll
        for (int j=0;j<4;j++)
          acc[i][j] = __builtin_amdgcn_mfma_f32_16x16x32_bf16(bvv[j], av[i], acc[i][j], 0,0,0);
    } else {
      #pragma unroll
      for (int i=0;i<4;i++)
        #pragma unroll
        for (int j=0;j<4;j++)
          acc[i][j] = __builtin_amdgcn_mfma_f32_16x16x32_bf16(av[i], bvv[j], acc[i][j], 0,0,0);
    }
    __builtin_amdgcn_s_setprio(0);
    if (t+1 < NT){
      *(uint4*)(Al[pb^1]+lo0)=ra0; *(uint4*)(Al[pb^1]+lo1)=ra1;
      *(uint4*)(Bl[pb^1]+lo0)=rb0; *(uint4*)(Bl[pb^1]+lo1)=rb1;
    }
    __syncthreads();
    pb ^= 1;
  }

  if (!sw){
    unsigned short* out = (p==0)? Qp : Kp;
    const float scl = (p==0)? 0.125f*LOG2E : 1.0f;
    #pragma unroll
    for (int i=0;i<4;i++)
      #pragma unroll
      for (int j=0;j<4;j++)
        #pragma unroll
        for (int jr=0;jr<4;jr++){
          int m = m0 + wr*64 + i*16 + l4*4 + jr;
          int n = n0 + wc*64 + j*16 + l15;
          float val = (acc[i][j][jr] + bias[n]) * scl;
          int b2 = m >> 11, s = m & (S-1), hh2 = n >> 6, d = n & 63;
          out[(((size_t)b2*H + hh2)*S + s)*HD + d] = f2bf(val);
        }
  } else {
    #pragma unroll
    for (int i=0;i<4;i++)
      #pragma unroll
      for (int j=0;j<4;j++)
        #pragma unroll
        for (int jr=0;jr<4;jr++){
          int n = n0 + wc*64 + j*16 + l4*4 + jr;
          int m = m0 + wr*64 + i*16 + l15;
          float val = acc[i][j][jr] + bias[n];
          int b2 = m >> 11, s = m & (S-1), hh2 = n >> 6, d = n & 63;
          VTp[(((size_t)b2*H + hh2)*HD + d)*S + s] = f2bf(val);
        }
  }
}

// ---------------- output GEMM: 128x64 tile, fp32 out ----------------
__global__ __launch_bounds__(256, 2) void out_gemm(const unsigned short* __restrict__ A,
    const unsigned short* __restrict__ WoT, const float* __restrict__ bo, float* __restrict__ out){
  __shared__ __align__(16) char Al[2][8192];
  __shared__ __align__(16) char Bl[2][4096];
  const int tid = threadIdx.x, lane = tid & 63, wv = tid >> 6;
  const int l15 = lane & 15, l4 = lane >> 4;
  const int wr = wv >> 1, wc = wv & 1;
  const int n0 = blockIdx.x * 64;
  const int m0 = blockIdx.y * 128;

  f32x4 acc[4][2];
  #pragma unroll
  for (int i=0;i<4;i++)
    #pragma unroll
    for (int j=0;j<2;j++) acc[i][j] = (f32x4){0.f,0.f,0.f,0.f};

  const char* ga[2]; const char* gbp;
  #pragma unroll
  for (int i=0;i<2;i++){
    int u = tid + i*256, c = u>>6, l = u&63;
    ga[i] = (const char*)A + ((size_t)(m0 + c*16 + (l&15))*DM + (l>>4)*8)*2;
  }
  {
    int c = tid>>6, l = tid&63;
    gbp = (const char*)WoT + ((size_t)(n0 + c*16 + (l&15))*DM + (l>>4)*8)*2;
  }
  const int lo0 = tid*16, lo1 = tid*16 + 4096;

  uint4 ra0 = *(const uint4*)ga[0], ra1 = *(const uint4*)ga[1], rb0 = *(const uint4*)gbp;
  *(uint4*)(Al[0]+lo0)=ra0; *(uint4*)(Al[0]+lo1)=ra1; *(uint4*)(Bl[0]+lo0)=rb0;
  __syncthreads();

  const int NT = DM/32;
  int pb = 0;
  for (int t=0;t<NT;t++){
    if (t+1 < NT){
      ra0 = *(const uint4*)(ga[0] + (size_t)(t+1)*64);
      ra1 = *(const uint4*)(ga[1] + (size_t)(t+1)*64);
      rb0 = *(const uint4*)(gbp  + (size_t)(t+1)*64);
    }
    short8_t av[4], bvv[2];
    #pragma unroll
    for (int i=0;i<4;i++) av[i]  = *(const short8_t*)(Al[pb] + (wr*4+i)*1024 + lane*16);
    #pragma unroll
    for (int j=0;j<2;j++) bvv[j] = *(const short8_t*)(Bl[pb] + (wc*2+j)*1024 + lane*16);
    __builtin_amdgcn_s_setprio(1);
    #pragma unroll
    for (int i=0;i<4;i++)
      #pragma unroll
      for (int j=0;j<2;j++)
        acc[i][j] = __builtin_amdgcn_mfma_f32_16x16x32_bf16(av[i], bvv[j], acc[i][j], 0,0,0);
    __builtin_amdgcn_s_setprio(0);
    if (t+1 < NT){
      *(uint4*)(Al[pb^1]+lo0)=ra0; *(uint4*)(Al[pb^1]+lo1)=ra1; *(uint4*)(Bl[pb^1]+lo0)=rb0;
    }
    __syncthreads();
    pb ^= 1;
  }

  #pragma unroll
  for (int i=0;i<4;i++)
    #pragma unroll
    for (int j=0;j<2;j++)
      #pragma unroll
      for (int jr=0;jr<4;jr++){
        int m = m0 + wr*64 + i*16 + l4*4 + jr;
        int n = n0 + wc*32 + j*16 + l15;
        out[(size_t)m*DM + n] = acc[i][j][jr] + bo[n];
      }
}

// ---------------- flash attention, 32x32 MFMA ----------------
// 4 waves x 32 q-rows = 128 q/block; KV tiles of 64; log2-domain online softmax,
// defer-max THR=8; sums via ones-MFMA; P distributed by cvt_pk + permlane32_swap.
__global__ __launch_bounds__(256, 2) void attn_fwd(const unsigned short* __restrict__ Qp,
    const unsigned short* __restrict__ Kp, const unsigned short* __restrict__ VTp,
    const unsigned long long* __restrict__ Mb, unsigned short* __restrict__ X){
  __shared__ __align__(16) char smem[32768];   // [K0,K1,V0,V1] 8KB each; epilogue reuses 16KB
  const int tid = threadIdx.x, lane = tid & 63, wv = tid >> 6;
  const int q31 = lane & 31, h = lane >> 5;
  const int bh = blockIdx.y, b = bh >> 4, hh = bh & 15;
  const int q0 = blockIdx.x * 128;
  const int qrow = q0 + wv*32 + q31;

  const unsigned short* Qb = Qp + ((size_t)bh*S + qrow)*HD;
  short8_t qf[4];
  #pragma unroll
  for (int ks=0;ks<4;ks++) qf[ks] = *(const short8_t*)(Qb + ks*16 + h*8);

  short8_t ones8;
  #pragma unroll
  for (int j2=0;j2<8;j2++) ones8[j2] = (short)0x3F80;

  f32x16 o0, o1, aS;
  #pragma unroll
  for (int r=0;r<16;r++){ o0[r]=0.f; o1[r]=0.f; aS[r]=0.f; }
  float mrun = -3.0e38f;

  const char* KsrcB = (const char*)(Kp + (size_t)bh*S*HD);
  const char* VsrcB = (const char*)(VTp + (size_t)bh*HD*S);
  const unsigned long long* mrow = Mb + ((size_t)b*S + qrow)*(S/64);

  // staging: K chunk c: kv = 32*(c>>2)+(l&31), d = (c&3)*16+(l>>5)*8; LDS = u*16
  const char* kg[2]; const char* vg[2]; int ldso[2];
  #pragma unroll
  for (int i=0;i<2;i++){
    int u = tid + i*256, c = u>>6, l = u&63;
    kg[i] = KsrcB + ((size_t)(32*(c>>2) + (l&31))*HD + (c&3)*16 + (l>>5)*8)*2;
    vg[i] = VsrcB + ((size_t)(32*(c>>2) + (l&31))*S  + (c&3)*16 + (l>>5)*8)*2;
    ldso[i] = u*16;
  }

  uint4 kr0 = *(const uint4*)kg[0], kr1 = *(const uint4*)kg[1];
  uint4 vr0 = *(const uint4*)vg[0], vr1 = *(const uint4*)vg[1];
  unsigned long long wnx = mrow[0];
  *(uint4*)(smem + ldso[0]) = kr0; *(uint4*)(smem + ldso[1]) = kr1;
  *(uint4*)(smem + 16384 + ldso[0]) = vr0; *(uint4*)(smem + 16384 + ldso[1]) = vr1;
  __syncthreads();

  const int NT = S/64;
  int pb = 0;
  for (int t=0; t<NT; ++t){
    unsigned long long wcur = wnx;
    if (t+1 < NT){
      kr0 = *(const uint4*)(kg[0] + (size_t)(t+1)*8192);
      kr1 = *(const uint4*)(kg[1] + (size_t)(t+1)*8192);
      vr0 = *(const uint4*)(vg[0] + (size_t)(t+1)*128);
      vr1 = *(const uint4*)(vg[1] + (size_t)(t+1)*128);
      wnx = mrow[t+1];
    }
    const char* kb = smem + pb*8192;
    const char* vb = smem + 16384 + pb*8192;

    f32x16 c0, c1;
    #pragma unroll
    for (int r=0;r<16;r++){ c0[r]=0.f; c1[r]=0.f; }
    __builtin_amdgcn_s_setprio(1);
    #pragma unroll
    for (int ks=0;ks<4;ks++){
      short8_t kf0 = *(const short8_t*)(kb + ks*1024 + lane*16);
      c0 = __builtin_amdgcn_mfma_f32_32x32x16_bf16(kf0, qf[ks], c0, 0,0,0);
      short8_t kf1 = *(const short8_t*)(kb + (4+ks)*1024 + lane*16);
      c1 = __builtin_amdgcn_mfma_f32_32x32x16_bf16(kf1, qf[ks], c1, 0,0,0);
    }
    __builtin_amdgcn_s_setprio(0);

    // max (log2 domain), defer-max THR=8
    float mf = c0[0];
    #pragma unroll
    for (int r=1;r<16;r++) mf = fmaxf(mf, c0[r]);
    #pragma unroll
    for (int r=0;r<16;r++) mf = fmaxf(mf, c1[r]);
    mf = fmaxf(mf, __shfl_xor(mf, 32));
    if (!__all(mf <= mrun + 8.0f)){
      float mnew = fmaxf(mrun, mf);
      float rs = ex2(mrun - mnew);
      mrun = mnew;
      #pragma unroll
      for (int r=0;r<16;r++){ o0[r]*=rs; o1[r]*=rs; }
      aS[0]*=rs;
    }

    // exp2 + bitmask zeroing
    unsigned long long wsh = wcur >> (4*h);
    unsigned mlo = (unsigned)wsh, mhi = (unsigned)(wsh >> 32);
    #pragma unroll
    for (int r=0;r<16;r++){
      const int bitc = (r&3) + 8*(r>>2);
      float e0 = ex2(c0[r] - mrun);
      float e1 = ex2(c1[r] - mrun);
      c0[r] = ((mlo >> bitc) & 1u) ? e0 : 0.f;
      c1[r] = ((mhi >> bitc) & 1u) ? e1 : 0.f;
    }

    // pack to bf16 pairs, redistribute into PV B-fragments via permlane32_swap
    unsigned w0[8], w1[8];
    #pragma unroll
    for (int m=0;m<8;m++){ w0[m] = pk2(c0[2*m], c0[2*m+1]); w1[m] = pk2(c1[2*m], c1[2*m+1]); }
    union Frag { short8_t s; unsigned w[4]; };
    Frag pf[4];
    { unsigned x=w0[0], y=w0[2]; pswap(x,y); pf[0].w[0]=x; pf[0].w[2]=y; }
    { unsigned x=w0[1], y=w0[3]; pswap(x,y); pf[0].w[1]=x; pf[0].w[3]=y; }
    { unsigned x=w0[4], y=w0[6]; pswap(x,y); pf[1].w[0]=x; pf[1].w[2]=y; }
    { unsigned x=w0[5], y=w0[7]; pswap(x,y); pf[1].w[1]=x; pf[1].w[3]=y; }
    { unsigned x=w1[0], y=w1[2]; pswap(x,y); pf[2].w[0]=x; pf[2].w[2]=y; }
    { unsigned x=w1[1], y=w1[3]; pswap(x,y); pf[2].w[1]=x; pf[2].w[3]=y; }
    { unsigned x=w1[4], y=w1[6]; pswap(x,y); pf[3].w[0]=x; pf[3].w[2]=y; }
    { unsigned x=w1[5], y=w1[7]; pswap(x,y); pf[3].w[1]=x; pf[3].w[3]=y; }

    __builtin_amdgcn_s_setprio(1);
    #pragma unroll
    for (int kvs=0;kvs<4;kvs++){
      aS = __builtin_amdgcn_mfma_f32_32x32x16_bf16(ones8, pf[kvs].s, aS, 0,0,0);
      short8_t vf0 = *(const short8_t*)(vb + kvs*1024 + lane*16);
      o0 = __builtin_amdgcn_mfma_f32_32x32x16_bf16(vf0, pf[kvs].s, o0, 0,0,0);
      short8_t vf1 = *(const short8_t*)(vb + (4+kvs)*1024 + lane*16);
      o1 = __builtin_amdgcn_mfma_f32_32x32x16_bf16(vf1, pf[kvs].s, o1, 0,0,0);
    }
    __builtin_amdgcn_s_setprio(0);

    if (t+1 < NT){
      char* kw = smem + (pb^1)*8192;
      char* vw = smem + 16384 + (pb^1)*8192;
      *(uint4*)(kw + ldso[0]) = kr0; *(uint4*)(kw + ldso[1]) = kr1;
      *(uint4*)(vw + ldso[0]) = vr0; *(uint4*)(vw + ldso[1]) = vr1;
    }
    __syncthreads();
    pb ^= 1;
  }

  // epilogue: normalize, stage rows in LDS (16B-slot XOR by row&7), coalesced store
  float inv = 1.0f / aS[0];
  const int ql = wv*32 + q31;
  #pragma unroll
  for (int m=0;m<8;m++){
    int d0 = ((2*m)&3) + 8*(m>>1) + 4*h;
    unsigned wa = pk2(o0[2*m]*inv, o0[2*m+1]*inv);
    *(unsigned*)(smem + ql*128 + (((d0>>3) ^ (ql&7))*16) + (d0&7)*2) = wa;
    int d1 = d0 + 32;
    unsigned wb2 = pk2(o1[2*m]*inv, o1[2*m+1]*inv);
    *(unsigned*)(smem + ql*128 + (((d1>>3) ^ (ql&7))*16) + (d1&7)*2) = wb2;
  }
  __syncthreads();
  #pragma unroll
  for (int it=0; it<4; it++){
    int u = it*256 + tid;
    int row = u>>3, cc = u&7;
    uint4 vvv = *(const uint4*)(smem + row*128 + cc*16);
    int g = cc ^ (row & 7);
    *(uint4*)(X + ((size_t)b*S + q0 + row)*DM + hh*HD + g*8) = vvv;
  }
}

// ---------------- launch ----------------
extern "C" void kernel_launch(void* const* d_in, const int* in_sizes, int n_in,
                              void* d_out, int out_size, void* d_ws, size_t ws_size,
                              hipStream_t stream){
  const float* query = (const float*)d_in[0];
  const float* key   = (const float*)d_in[1];
  const float* value = (const float*)d_in[2];
  const int*   mask  = (const int*)d_in[3];
  const float* Wq = (const float*)d_in[4];
  const float* bq = (const float*)d_in[5];
  const float* Wk = (const float*)d_in[6];
  const float* bk = (const float*)d_in[7];
  const float* Wv = (const float*)d_in[8];
  const float* bvp= (const float*)d_in[9];
  const float* Wo = (const float*)d_in[10];
  const float* bo = (const float*)d_in[11];

  const size_t NE = (size_t)NB*S*DM;       // 4194304
  const size_t WE = (size_t)DM*DM;         // 1048576
  const size_t ME = (size_t)NB*S*S;        // 8388608

  char* w = (char*)d_ws;
  unsigned short* qb  = (unsigned short*)w; w += NE*2;
  unsigned short* kb  = (unsigned short*)w; w += NE*2;
  unsigned short* vb  = (unsigned short*)w; w += NE*2;
  unsigned short* WT  = (unsigned short*)w; w += 3*WE*2;
  unsigned short* WoT = (unsigned short*)w; w += WE*2;
  unsigned short* m16 = (unsigned short*)w; w += (ME/16)*2;
  unsigned short* Qp  = (unsigned short*)w; w += NE*2;
  unsigned short* Kp  = (unsigned short*)w; w += NE*2;
  unsigned short* VTp = (unsigned short*)w; w += NE*2;
  unsigned short* xb  = (unsigned short*)w; w += NE*2;

  prep<<<12288, 256, 0, stream>>>(query, key, value, mask, Wq, Wk, Wv, Wo,
                                  qb, kb, vb, WT, WoT, m16);
  qkv_gemm<<<dim3(24,32), 256, 0, stream>>>(qb, kb, vb, WT, bq, bk, bvp, Qp, Kp, VTp);
  attn_fwd<<<dim3(S/128, NB*H), 256, 0, stream>>>(Qp, Kp, VTp,
                                  (const unsigned long long*)m16, xb);
  out_gemm<<<dim3(DM/64, (NB*S)/128), 256, 0, stream>>>(xb, WoT, bo, (float*)d_out);
}